// Round 5
// baseline (699.488 us; speedup 1.0000x reference)
//
#include <hip/hip_runtime.h>
#include <hip/hip_bf16.h>

#define N_NODES 50000
#define N_EDGES 800000
#define DIM 128
#define NREL 8
#define KTOT 1152              // (NREL+1)*DIM
#define NRSEG (N_NODES * NREL) // 400000
#define BN_EPS 1e-5f
#define ATSTRIDE 1160          // padded LDS row stride (elems): +4 banks/row

typedef __attribute__((ext_vector_type(8))) short bf16x8;
typedef __attribute__((ext_vector_type(16))) float f32x16;

__device__ inline float b2f(short s) {
    union { unsigned u; float f; } t;
    t.u = ((unsigned)(unsigned short)s) << 16;
    return t.f;
}
__device__ inline short f2b(float f) {
    __hip_bfloat16 h = __float2bfloat16(f);
    return *reinterpret_cast<short*>(&h);
}

// ---------------- CSR build ----------------

__global__ void k_hist(const int* __restrict__ ei, const int* __restrict__ et,
                       int* __restrict__ cnt) {
    int e = blockIdx.x * 256 + threadIdx.x;
    if (e < N_EDGES) {
        int tgt = ei[N_EDGES + e];
        int r = et[e];
        atomicAdd(&cnt[tgt * NREL + r], 1);
    }
}

__global__ void k_alloc(const int* __restrict__ cnt, int* __restrict__ offs,
                        int* __restrict__ cursor) {
    int i = blockIdx.x * 256 + threadIdx.x;
    int lane = threadIdx.x & 63;
    int c = (i < NRSEG) ? cnt[i] : 0;
    int incl = c;
    #pragma unroll
    for (int d = 1; d < 64; d <<= 1) {
        int t = __shfl_up(incl, d, 64);
        if (lane >= d) incl += t;
    }
    int total = __shfl(incl, 63, 64);
    int base = 0;
    if (lane == 63) base = atomicAdd(cursor, total);
    base = __shfl(base, 63, 64);
    if (i < NRSEG) offs[i] = base + incl - c;
}

__global__ void k_fill(const int* __restrict__ ei, const int* __restrict__ et,
                       const int* __restrict__ offs, int* __restrict__ fillcur,
                       int* __restrict__ sorted) {
    int e = blockIdx.x * 256 + threadIdx.x;
    if (e < N_EDGES) {
        int src = ei[e];
        int tgt = ei[N_EDGES + e];
        int comp = tgt * NREL + et[e];
        int pos = atomicAdd(&fillcur[comp], 1);
        sorted[offs[comp] + pos] = src;
    }
}

// ---------------- weight conversion: Bt[o][r*128+i] = W[r][i][o]; Bt[o][1024+i] = root[i][o]
__global__ void k_wconv(const float* __restrict__ W, const float* __restrict__ root,
                        __hip_bfloat16* __restrict__ Bt) {
    int idx = blockIdx.x * 256 + threadIdx.x;
    if (idx >= DIM * KTOT) return;
    int o = idx / KTOT, k = idx % KTOT;
    float v;
    if (k < NREL * DIM) {
        int r = k >> 7, i = k & 127;
        v = W[(r * DIM + i) * DIM + o];
    } else {
        int i = k - NREL * DIM;
        v = root[i * DIM + o];
    }
    Bt[idx] = __float2bfloat16(v);
}

// ---------------- cast fp32 input -> bf16
__global__ void k_cast(const float* __restrict__ in, __hip_bfloat16* __restrict__ out) {
    int i = (blockIdx.x * 256 + threadIdx.x) * 4;
    if (i >= N_NODES * DIM) return;
    float4 v = *(const float4*)&in[i];
    short4 o;
    o.x = f2b(v.x); o.y = f2b(v.y); o.z = f2b(v.z); o.w = f2b(v.w);
    *(short4*)&out[i] = o;
}

// ---------------- cast bf16 h + BN(scale,shift)+ReLU -> bf16
__global__ void k_cast2(const __hip_bfloat16* __restrict__ in, const float* __restrict__ bn,
                        __hip_bfloat16* __restrict__ out) {
    int i = (blockIdx.x * 256 + threadIdx.x) * 8;
    if (i >= N_NODES * DIM) return;
    bf16x8 v = *(const bf16x8*)&in[i];
    int ch = i & 127;
    bf16x8 o;
    #pragma unroll
    for (int j = 0; j < 8; ++j) {
        float f = b2f(v[j]);
        f = fmaxf(f * bn[ch + j] + bn[128 + ch + j], 0.f);
        o[j] = f2b(f);
    }
    *(bf16x8*)&out[i] = o;
}

// ---------------- fused RGCN layer v2: 32-node tile, ONE barrier.
// Gather phase: 16 units (16 lanes each); unit u stages rows u and u+16,
// running all 8 relation chains concurrently (8-way unrolled, independent
// loads); each lane owns 8 channels -> no cross-lane reduction. Full
// At[32][1152] (padded stride 1160) lands in LDS. One __syncthreads.
// GEMM phase: 4 waves, one 32x32 output tile each, K=1152 from LDS;
// B-frag direct from L2-resident Bt. Epilogue: bias, bf16 h, BN stats.
// MFMA 32x32x16: A-frag lane l: row=l&31, k=(l>>5)*8+j; B-frag: col=l&31,
// same k. C/D: col=lane&31, row=(reg&3)+8*(reg>>2)+4*(lane>>5).
__global__ __launch_bounds__(256, 2) void k_fused2(
        const __hip_bfloat16* __restrict__ xb,
        const int* __restrict__ cnt, const int* __restrict__ offs,
        const int* __restrict__ sorted,
        const __hip_bfloat16* __restrict__ Bt,
        const float* __restrict__ bias,
        __hip_bfloat16* __restrict__ h, float* __restrict__ stats) {
    __shared__ __hip_bfloat16 At[32 * ATSTRIDE];   // 74.2 KB -> 2 blocks/CU
    int tid = threadIdx.x;
    int n0 = blockIdx.x * 32;
    int unit = tid >> 4, il = tid & 15;
    int ubase = (tid & 63) & 48;                   // unit's lane base within wave

    #pragma unroll 1
    for (int rr = 0; rr < 2; ++rr) {
        int vi = unit + rr * 16;
        int node = n0 + vi;
        bool ok = node < N_NODES;
        // segment meta: lane il<8 of the unit loads (c,o) for relation il
        int c = 0, o = 0;
        if (ok && il < 8) {
            c = cnt[node * NREL + il];
            o = offs[node * NREL + il];
        }
        int c8[8], o8[8];
        #pragma unroll
        for (int r = 0; r < 8; ++r) {
            c8[r] = __shfl(c, ubase + r, 64);
            o8[r] = __shfl(o, ubase + r, 64);
        }
        int mx = 0;
        #pragma unroll
        for (int r = 0; r < 8; ++r) mx = max(mx, c8[r]);

        float s[8][8];
        #pragma unroll
        for (int r = 0; r < 8; ++r)
            #pragma unroll
            for (int j = 0; j < 8; ++j) s[r][j] = 0.f;

        // all 8 relation chains advance together: 8 independent gathers/iter
        for (int i = 0; i < mx; ++i) {
            #pragma unroll
            for (int r = 0; r < 8; ++r) {
                if (i < c8[r]) {
                    int idx = sorted[o8[r] + i];
                    bf16x8 rv = *(const bf16x8*)&xb[(size_t)idx * DIM + il * 8];
                    #pragma unroll
                    for (int j = 0; j < 8; ++j) s[r][j] += b2f(rv[j]);
                }
            }
        }
        // write means
        #pragma unroll
        for (int r = 0; r < 8; ++r) {
            float inv = (c8[r] > 0) ? 1.f / (float)c8[r] : 0.f;
            bf16x8 ov;
            #pragma unroll
            for (int j = 0; j < 8; ++j) ov[j] = f2b(s[r][j] * inv);
            *(bf16x8*)&At[vi * ATSTRIDE + r * DIM + il * 8] = ov;
        }
        // self slice
        bf16x8 sv = {};
        if (ok) sv = *(const bf16x8*)&xb[(size_t)node * DIM + il * 8];
        *(bf16x8*)&At[vi * ATSTRIDE + NREL * DIM + il * 8] = sv;
    }

    __syncthreads();

    // ---- GEMM phase: wave wid -> cols [wid*32, wid*32+32), rows n0..n0+31
    int lane = tid & 63, wid = tid >> 6;
    int half = lane >> 5, l31 = lane & 31;
    const __hip_bfloat16* bBase = Bt + (size_t)(wid * 32 + l31) * KTOT + half * 8;
    const __hip_bfloat16* aBase = &At[l31 * ATSTRIDE + half * 8];
    f32x16 acc = {};
    #pragma unroll
    for (int r = 0; r < 9; ++r) {
        #pragma unroll
        for (int ks = 0; ks < 8; ++ks) {
            bf16x8 a = *(const bf16x8*)(aBase + r * DIM + ks * 16);
            bf16x8 b = *(const bf16x8*)(bBase + r * DIM + ks * 16);
            acc = __builtin_amdgcn_mfma_f32_32x32x16_bf16(a, b, acc, 0, 0, 0);
        }
    }

    // ---- epilogue: bias, store h (bf16), BN stats
    int col = wid * 32 + l31;
    float bv = bias[col];
    float s1 = 0.f, s2 = 0.f;
    #pragma unroll
    for (int reg = 0; reg < 16; ++reg) {
        int row = n0 + (reg & 3) + 8 * (reg >> 2) + 4 * half;
        float v = acc[reg] + bv;
        if (row < N_NODES) {
            h[(size_t)row * DIM + col] = __float2bfloat16(v);
            s1 += v; s2 += v * v;
        }
    }
    s1 += __shfl_xor(s1, 32, 64);
    s2 += __shfl_xor(s2, 32, 64);
    if (half == 0) {
        atomicAdd(&stats[col], s1);
        atomicAdd(&stats[128 + col], s2);
    }
}

__global__ void k_bnfinal(const float* __restrict__ stats, const float* __restrict__ g,
                          const float* __restrict__ be, float* __restrict__ bn) {
    int c = threadIdx.x;
    float mean = stats[c] / (float)N_NODES;
    float var = stats[128 + c] / (float)N_NODES - mean * mean;
    float a = g[c] * rsqrtf(var + BN_EPS);
    bn[c] = a;
    bn[128 + c] = be[c] - mean * a;
}

// ---------------- classifier: out[v,0:2] = relu(bn(h2[v])) @ cw + cb
__global__ void k_classifier(const __hip_bfloat16* __restrict__ h, const float* __restrict__ bn,
                             const float* __restrict__ cw, const float* __restrict__ cb,
                             float* __restrict__ out) {
    int w = blockIdx.x * 4 + (threadIdx.x >> 6);
    int lane = threadIdx.x & 63;
    if (w >= N_NODES) return;
    int c = lane * 2;
    __hip_bfloat162 hv = *(const __hip_bfloat162*)&h[(size_t)w * DIM + c];
    float x0 = __bfloat162float(hv.x), x1 = __bfloat162float(hv.y);
    float p0 = fmaxf(x0 * bn[c] + bn[128 + c], 0.f);
    float p1 = fmaxf(x1 * bn[c + 1] + bn[128 + c + 1], 0.f);
    float acc0 = p0 * cw[c * 2] + p1 * cw[(c + 1) * 2];
    float acc1 = p0 * cw[c * 2 + 1] + p1 * cw[(c + 1) * 2 + 1];
    #pragma unroll
    for (int d = 32; d; d >>= 1) {
        acc0 += __shfl_down(acc0, d, 64);
        acc1 += __shfl_down(acc1, d, 64);
    }
    if (lane == 0) {
        out[w * 2] = acc0 + cb[0];
        out[w * 2 + 1] = acc1 + cb[1];
    }
}

extern "C" void kernel_launch(void* const* d_in, const int* in_sizes, int n_in,
                              void* d_out, int out_size, void* d_ws, size_t ws_size,
                              hipStream_t stream) {
    const float* x    = (const float*)d_in[0];
    const int*   ei   = (const int*)d_in[1];
    const int*   et   = (const int*)d_in[2];
    const float* w1   = (const float*)d_in[3];
    const float* root1= (const float*)d_in[4];
    const float* b1   = (const float*)d_in[5];
    const float* g1   = (const float*)d_in[6];
    const float* be1  = (const float*)d_in[7];
    const float* w2   = (const float*)d_in[8];
    const float* root2= (const float*)d_in[9];
    const float* b2   = (const float*)d_in[10];
    const float* g2   = (const float*)d_in[11];
    const float* be2  = (const float*)d_in[12];
    const float* cw   = (const float*)d_in[13];
    const float* cb   = (const float*)d_in[14];
    float* out = (float*)d_out;

    char* ws = (char*)d_ws;
    size_t off = 0;
    auto alloc = [&](size_t bytes) -> char* {
        char* p = ws + off;
        off += (bytes + 255) & ~(size_t)255;
        return p;
    };
    // zeroed region first
    int*   cnt     = (int*)alloc((size_t)NRSEG * 4);
    int*   fillcur = (int*)alloc((size_t)NRSEG * 4);
    int*   cursor  = (int*)alloc(256);
    float* stats1  = (float*)alloc(1024);
    float* stats2  = (float*)alloc(1024);
    size_t zero_bytes = off;
    int*   offs    = (int*)alloc((size_t)NRSEG * 4);
    float* bn1     = (float*)alloc(1024);
    float* bn2     = (float*)alloc(1024);
    __hip_bfloat16* Bt1 = (__hip_bfloat16*)alloc((size_t)DIM * KTOT * 2);
    __hip_bfloat16* Bt2 = (__hip_bfloat16*)alloc((size_t)DIM * KTOT * 2);
    int*   sorted  = (int*)alloc((size_t)N_EDGES * 4);
    __hip_bfloat16* h1 = (__hip_bfloat16*)alloc((size_t)N_NODES * DIM * 2);
    __hip_bfloat16* h2 = (__hip_bfloat16*)alloc((size_t)N_NODES * DIM * 2);
    __hip_bfloat16* xb = (__hip_bfloat16*)alloc((size_t)N_NODES * DIM * 2);

    hipMemsetAsync(d_ws, 0, zero_bytes, stream);

    k_hist<<<(N_EDGES + 255) / 256, 256, 0, stream>>>(ei, et, cnt);
    k_alloc<<<(NRSEG + 255) / 256, 256, 0, stream>>>(cnt, offs, cursor);
    k_fill<<<(N_EDGES + 255) / 256, 256, 0, stream>>>(ei, et, offs, fillcur, sorted);
    k_wconv<<<(DIM * KTOT + 255) / 256, 256, 0, stream>>>(w1, root1, Bt1);
    k_wconv<<<(DIM * KTOT + 255) / 256, 256, 0, stream>>>(w2, root2, Bt2);

    int fused_grid = (N_NODES + 31) / 32;   // 1563

    // layer 1
    k_cast<<<(N_NODES * DIM / 4 + 255) / 256, 256, 0, stream>>>(x, xb);
    k_fused2<<<fused_grid, 256, 0, stream>>>(xb, cnt, offs, sorted, Bt1, b1, h1, stats1);
    k_bnfinal<<<1, 128, 0, stream>>>(stats1, g1, be1, bn1);

    // layer 2
    k_cast2<<<(N_NODES * DIM / 8 + 255) / 256, 256, 0, stream>>>(h1, bn1, xb);
    k_fused2<<<fused_grid, 256, 0, stream>>>(xb, cnt, offs, sorted, Bt2, b2, h2, stats2);
    k_bnfinal<<<1, 128, 0, stream>>>(stats2, g2, be2, bn2);

    k_classifier<<<(N_NODES + 3) / 4, 256, 0, stream>>>(h2, bn2, cw, cb, out);
}

// Round 7
// 620.874 us; speedup vs baseline: 1.1266x; 1.1266x over previous
//
#include <hip/hip_runtime.h>
#include <hip/hip_bf16.h>

#define N_NODES 50000
#define N_EDGES 800000
#define DIM 128
#define NREL 8
#define KTOT 1152              // (NREL+1)*DIM
#define NRSEG (N_NODES * NREL) // 400000
#define BN_EPS 1e-5f

typedef __attribute__((ext_vector_type(8))) short bf16x8;
typedef __attribute__((ext_vector_type(16))) float f32x16;

__device__ inline short f2b(float f) {
    __hip_bfloat16 h = __float2bfloat16(f);
    return *reinterpret_cast<short*>(&h);
}
__device__ inline void acc4(float4& s, const float4& v) {
    s.x += v.x; s.y += v.y; s.z += v.z; s.w += v.w;
}

// ---------------- CSR build ----------------

__global__ void k_hist(const int* __restrict__ ei, const int* __restrict__ et,
                       int* __restrict__ cnt) {
    int e = blockIdx.x * 256 + threadIdx.x;
    if (e < N_EDGES) {
        int tgt = ei[N_EDGES + e];
        int r = et[e];
        atomicAdd(&cnt[tgt * NREL + r], 1);
    }
}

__global__ void k_alloc(const int* __restrict__ cnt, int* __restrict__ offs,
                        int* __restrict__ cursor) {
    int i = blockIdx.x * 256 + threadIdx.x;
    int lane = threadIdx.x & 63;
    int c = (i < NRSEG) ? cnt[i] : 0;
    int incl = c;
    #pragma unroll
    for (int d = 1; d < 64; d <<= 1) {
        int t = __shfl_up(incl, d, 64);
        if (lane >= d) incl += t;
    }
    int total = __shfl(incl, 63, 64);
    int base = 0;
    if (lane == 63) base = atomicAdd(cursor, total);
    base = __shfl(base, 63, 64);
    if (i < NRSEG) offs[i] = base + incl - c;
}

__global__ void k_fill(const int* __restrict__ ei, const int* __restrict__ et,
                       const int* __restrict__ offs, int* __restrict__ fillcur,
                       int* __restrict__ sorted) {
    int e = blockIdx.x * 256 + threadIdx.x;
    if (e < N_EDGES) {
        int src = ei[e];
        int tgt = ei[N_EDGES + e];
        int comp = tgt * NREL + et[e];
        int pos = atomicAdd(&fillcur[comp], 1);
        sorted[offs[comp] + pos] = src;
    }
}

// ---------------- weight conversion (both layers in one launch):
// Bt[o][r*128+i] = W[r][i][o]; Bt[o][1024+i] = root[i][o]
__global__ void k_wconv2(const float* __restrict__ W1, const float* __restrict__ root1,
                         __hip_bfloat16* __restrict__ Bt1,
                         const float* __restrict__ W2, const float* __restrict__ root2,
                         __hip_bfloat16* __restrict__ Bt2) {
    int gidx = blockIdx.x * 256 + threadIdx.x;
    int which = gidx >= DIM * KTOT;                 // grid is exactly 2*576 blocks
    int idx = which ? gidx - DIM * KTOT : gidx;
    const float* W = which ? W2 : W1;
    const float* root = which ? root2 : root1;
    __hip_bfloat16* Bt = which ? Bt2 : Bt1;
    int o = idx / KTOT, k = idx % KTOT;
    float v;
    if (k < NREL * DIM) {
        int r = k >> 7, i = k & 127;
        v = W[(r * DIM + i) * DIM + o];
    } else {
        int i = k - NREL * DIM;
        v = root[i * DIM + o];
    }
    Bt[idx] = __float2bfloat16(v);
}

// ---------------- buildA3: fp32 gather, no shuffles, no converts in loop.
// 8 units of 32 lanes per block; unit = one node; lane owns 4 channels.
// Relations processed in pairs (2 chains) with 2-edge unroll = 8 loads in flight.
__global__ __launch_bounds__(256) void k_buildA3(
        const float* __restrict__ xr,
        const int* __restrict__ cnt, const int* __restrict__ offs,
        const int* __restrict__ sorted,
        __hip_bfloat16* __restrict__ A) {
    int tid = threadIdx.x;
    int unit = tid >> 5, il = tid & 31;
    int node = blockIdx.x * 8 + unit;
    if (node >= N_NODES) return;
    int ch = il * 4;
    int c = 0, o = 0;
    if (il < 8) {
        c = cnt[node * NREL + il];
        o = offs[node * NREL + il];
    }
    int ubase = (tid & 63) & 32;       // unit's base lane within its wave
    int c8[8], o8[8];
    #pragma unroll
    for (int r = 0; r < 8; ++r) {
        c8[r] = __shfl(c, ubase + r, 64);
        o8[r] = __shfl(o, ubase + r, 64);
    }
    const float* xch = xr + ch;
    __hip_bfloat16* arow = A + (size_t)node * KTOT + ch;

    #pragma unroll
    for (int rp = 0; rp < 4; ++rp) {
        int ca = c8[2 * rp], oa = o8[2 * rp];
        int cb = c8[2 * rp + 1], ob = o8[2 * rp + 1];
        float4 s0 = {0.f, 0.f, 0.f, 0.f}, s1 = {0.f, 0.f, 0.f, 0.f};
        int mx = max(ca, cb);
        for (int i = 0; i < mx; i += 2) {
            int ia0 = (i < ca) ? sorted[oa + i] : -1;
            int ia1 = (i + 1 < ca) ? sorted[oa + i + 1] : -1;
            int ib0 = (i < cb) ? sorted[ob + i] : -1;
            int ib1 = (i + 1 < cb) ? sorted[ob + i + 1] : -1;
            float4 va0 = {0,0,0,0}, va1 = {0,0,0,0}, vb0 = {0,0,0,0}, vb1 = {0,0,0,0};
            if (ia0 >= 0) va0 = *(const float4*)(xch + (size_t)ia0 * DIM);
            if (ia1 >= 0) va1 = *(const float4*)(xch + (size_t)ia1 * DIM);
            if (ib0 >= 0) vb0 = *(const float4*)(xch + (size_t)ib0 * DIM);
            if (ib1 >= 0) vb1 = *(const float4*)(xch + (size_t)ib1 * DIM);
            acc4(s0, va0); acc4(s0, va1);
            acc4(s1, vb0); acc4(s1, vb1);
        }
        float inva = (ca > 0) ? 1.f / (float)ca : 0.f;
        float invb = (cb > 0) ? 1.f / (float)cb : 0.f;
        short4 outa, outb;
        outa.x = f2b(s0.x * inva); outa.y = f2b(s0.y * inva);
        outa.z = f2b(s0.z * inva); outa.w = f2b(s0.w * inva);
        outb.x = f2b(s1.x * invb); outb.y = f2b(s1.y * invb);
        outb.z = f2b(s1.z * invb); outb.w = f2b(s1.w * invb);
        *(short4*)(arow + (2 * rp) * DIM) = outa;
        *(short4*)(arow + (2 * rp + 1) * DIM) = outb;
    }
    // self slice
    float4 sv = *(const float4*)(xch + (size_t)node * DIM);
    short4 so;
    so.x = f2b(sv.x); so.y = f2b(sv.y); so.z = f2b(sv.z); so.w = f2b(sv.w);
    *(short4*)(arow + NREL * DIM) = so;
}

// ---------------- GEMM v3: barrier-free, one wave per 32 rows x 64 cols.
// Grid = 1563 row-tiles x 2 col-tiles = 3126 one-wave blocks (~12 waves/CU).
// Epilogue fuses bias add, fp32 h write, and BN-stat atomics.
// mfma_f32_32x32x16_bf16: A-frag lane l: row=l&31, k=(l>>5)*8+j; B-frag:
// col=l&31, same k. C/D: col=lane&31, row=(reg&3)+8*(reg>>2)+4*(lane>>5).
#define G3LOAD(kc, aB, bB)                                                    \
    {                                                                         \
        _Pragma("unroll")                                                     \
        for (int s = 0; s < 2; ++s) {                                         \
            int ko = ((kc) + s) * 16;                                         \
            aB[s] = *(const bf16x8*)(aBase + ko);                             \
            bB[s][0] = *(const bf16x8*)(bBase0 + ko);                         \
            bB[s][1] = *(const bf16x8*)(bBase1 + ko);                         \
        }                                                                     \
    }

#define G3MFMA(aB, bB)                                                        \
    {                                                                         \
        _Pragma("unroll")                                                     \
        for (int s = 0; s < 2; ++s) {                                         \
            acc0 = __builtin_amdgcn_mfma_f32_32x32x16_bf16(aB[s], bB[s][0], acc0, 0, 0, 0); \
            acc1 = __builtin_amdgcn_mfma_f32_32x32x16_bf16(aB[s], bB[s][1], acc1, 0, 0, 0); \
        }                                                                     \
    }

__global__ __launch_bounds__(64) void k_gemm3(const __hip_bfloat16* __restrict__ A,
                                              const __hip_bfloat16* __restrict__ Bt,
                                              const float* __restrict__ bias,
                                              float* __restrict__ h,
                                              float* __restrict__ stats) {
    int lane = threadIdx.x;
    int rt = blockIdx.x >> 1, ct = blockIdx.x & 1;
    int m0 = rt * 32, c0 = ct * 64;
    int half = lane >> 5, l31 = lane & 31;
    int arow = m0 + l31;
    if (arow >= N_NODES) arow = N_NODES - 1;   // clamp loads; stores guarded
    const __hip_bfloat16* aBase = A + (size_t)arow * KTOT + half * 8;
    const __hip_bfloat16* bBase0 = Bt + (size_t)(c0 + l31) * KTOT + half * 8;
    const __hip_bfloat16* bBase1 = Bt + (size_t)(c0 + 32 + l31) * KTOT + half * 8;

    f32x16 acc0 = {}, acc1 = {};
    bf16x8 aA[2], aB2[2];
    bf16x8 bA[2][2], bB2[2][2];

    G3LOAD(0, aA, bA);
    // 72 k-steps of K=16 -> 36 chunks of 2, as 18 chunk-pairs
    for (int c = 0; c < 72; c += 4) {
        G3LOAD(c + 2, aB2, bB2);
        G3MFMA(aA, bA);
        if (c + 4 < 72) G3LOAD(c + 4, aA, bA);
        G3MFMA(aB2, bB2);
    }

    int col0 = c0 + l31, col1 = c0 + 32 + l31;
    float bv0 = bias[col0], bv1 = bias[col1];
    float s1a = 0.f, s2a = 0.f, s1b = 0.f, s2b = 0.f;
    #pragma unroll
    for (int reg = 0; reg < 16; ++reg) {
        int row = m0 + (reg & 3) + 8 * (reg >> 2) + 4 * half;
        if (row < N_NODES) {
            float v0 = acc0[reg] + bv0;
            float v1 = acc1[reg] + bv1;
            h[(size_t)row * DIM + col0] = v0;
            h[(size_t)row * DIM + col1] = v1;
            s1a += v0; s2a += v0 * v0;
            s1b += v1; s2b += v1 * v1;
        }
    }
    s1a += __shfl_xor(s1a, 32, 64); s2a += __shfl_xor(s2a, 32, 64);
    s1b += __shfl_xor(s1b, 32, 64); s2b += __shfl_xor(s2b, 32, 64);
    if (half == 0) {
        atomicAdd(&stats[col0], s1a);
        atomicAdd(&stats[128 + col0], s2a);
        atomicAdd(&stats[col1], s1b);
        atomicAdd(&stats[128 + col1], s2b);
    }
}

// ---------------- castbn: xr = relu(bn(h)) in fp32; bn derived inline from stats
__global__ void k_castbn(const float* __restrict__ h, const float* __restrict__ stats,
                         const float* __restrict__ g, const float* __restrict__ be,
                         float* __restrict__ xr) {
    int i = (blockIdx.x * 256 + threadIdx.x) * 4;
    if (i >= N_NODES * DIM) return;
    int ch = i & 127;
    float4 v = *(const float4*)&h[i];
    float4 sm = *(const float4*)&stats[ch];
    float4 sq = *(const float4*)&stats[128 + ch];
    float4 gg = *(const float4*)&g[ch];
    float4 bb = *(const float4*)&be[ch];
    const float invn = 1.f / (float)N_NODES;
    float m, var, a, b;
    float4 o;
    m = sm.x * invn; var = sq.x * invn - m * m; a = gg.x * rsqrtf(var + BN_EPS); b = bb.x - m * a;
    o.x = fmaxf(v.x * a + b, 0.f);
    m = sm.y * invn; var = sq.y * invn - m * m; a = gg.y * rsqrtf(var + BN_EPS); b = bb.y - m * a;
    o.y = fmaxf(v.y * a + b, 0.f);
    m = sm.z * invn; var = sq.z * invn - m * m; a = gg.z * rsqrtf(var + BN_EPS); b = bb.z - m * a;
    o.z = fmaxf(v.z * a + b, 0.f);
    m = sm.w * invn; var = sq.w * invn - m * m; a = gg.w * rsqrtf(var + BN_EPS); b = bb.w - m * a;
    o.w = fmaxf(v.w * a + b, 0.f);
    *(float4*)&xr[i] = o;
}

// ---------------- classifier: out[v,0:2] = relu(bn(h2[v])) @ cw + cb, bn inline
__global__ void k_classifier(const float* __restrict__ h, const float* __restrict__ stats,
                             const float* __restrict__ g, const float* __restrict__ be,
                             const float* __restrict__ cw, const float* __restrict__ cb,
                             float* __restrict__ out) {
    int w = blockIdx.x * 4 + (threadIdx.x >> 6);
    int lane = threadIdx.x & 63;
    if (w >= N_NODES) return;
    int c = lane * 2;
    const float invn = 1.f / (float)N_NODES;
    float2 v = *(const float2*)&h[(size_t)w * DIM + c];
    float2 sm = *(const float2*)&stats[c];
    float2 sq = *(const float2*)&stats[128 + c];
    float2 gg = *(const float2*)&g[c];
    float2 bb = *(const float2*)&be[c];
    float m0 = sm.x * invn, var0 = sq.x * invn - m0 * m0;
    float a0 = gg.x * rsqrtf(var0 + BN_EPS), b0 = bb.x - m0 * a0;
    float m1 = sm.y * invn, var1 = sq.y * invn - m1 * m1;
    float a1 = gg.y * rsqrtf(var1 + BN_EPS), b1 = bb.y - m1 * a1;
    float p0 = fmaxf(v.x * a0 + b0, 0.f);
    float p1 = fmaxf(v.y * a1 + b1, 0.f);
    float acc0 = p0 * cw[c * 2] + p1 * cw[(c + 1) * 2];
    float acc1 = p0 * cw[c * 2 + 1] + p1 * cw[(c + 1) * 2 + 1];
    #pragma unroll
    for (int d = 32; d; d >>= 1) {
        acc0 += __shfl_down(acc0, d, 64);
        acc1 += __shfl_down(acc1, d, 64);
    }
    if (lane == 0) {
        out[w * 2] = acc0 + cb[0];
        out[w * 2 + 1] = acc1 + cb[1];
    }
}

extern "C" void kernel_launch(void* const* d_in, const int* in_sizes, int n_in,
                              void* d_out, int out_size, void* d_ws, size_t ws_size,
                              hipStream_t stream) {
    const float* x    = (const float*)d_in[0];
    const int*   ei   = (const int*)d_in[1];
    const int*   et   = (const int*)d_in[2];
    const float* w1   = (const float*)d_in[3];
    const float* root1= (const float*)d_in[4];
    const float* b1   = (const float*)d_in[5];
    const float* g1   = (const float*)d_in[6];
    const float* be1  = (const float*)d_in[7];
    const float* w2   = (const float*)d_in[8];
    const float* root2= (const float*)d_in[9];
    const float* b2   = (const float*)d_in[10];
    const float* g2   = (const float*)d_in[11];
    const float* be2  = (const float*)d_in[12];
    const float* cw   = (const float*)d_in[13];
    const float* cb   = (const float*)d_in[14];
    float* out = (float*)d_out;

    char* ws = (char*)d_ws;
    size_t off = 0;
    auto alloc = [&](size_t bytes) -> char* {
        char* p = ws + off;
        off += (bytes + 255) & ~(size_t)255;
        return p;
    };
    // zeroed region first
    int*   cnt     = (int*)alloc((size_t)NRSEG * 4);
    int*   fillcur = (int*)alloc((size_t)NRSEG * 4);
    int*   cursor  = (int*)alloc(256);
    float* stats1  = (float*)alloc(1024);
    float* stats2  = (float*)alloc(1024);
    size_t zero_bytes = off;
    int*   offs    = (int*)alloc((size_t)NRSEG * 4);
    __hip_bfloat16* Bt1 = (__hip_bfloat16*)alloc((size_t)DIM * KTOT * 2);
    __hip_bfloat16* Bt2 = (__hip_bfloat16*)alloc((size_t)DIM * KTOT * 2);
    int*   sorted  = (int*)alloc((size_t)N_EDGES * 4);
    float* h1      = (float*)alloc((size_t)N_NODES * DIM * 4);
    float* h2      = (float*)alloc((size_t)N_NODES * DIM * 4);
    float* xr      = (float*)alloc((size_t)N_NODES * DIM * 4);
    __hip_bfloat16* A = (__hip_bfloat16*)alloc((size_t)N_NODES * KTOT * 2);

    hipMemsetAsync(d_ws, 0, zero_bytes, stream);

    k_hist<<<(N_EDGES + 255) / 256, 256, 0, stream>>>(ei, et, cnt);
    k_alloc<<<(NRSEG + 255) / 256, 256, 0, stream>>>(cnt, offs, cursor);
    k_fill<<<(N_EDGES + 255) / 256, 256, 0, stream>>>(ei, et, offs, fillcur, sorted);
    k_wconv2<<<2 * DIM * KTOT / 256, 256, 0, stream>>>(w1, root1, Bt1, w2, root2, Bt2);

    int bA_grid = (N_NODES + 7) / 8;        // 6250
    int gemm_grid = ((N_NODES + 31) / 32) * 2;  // 3126 one-wave blocks

    // layer 1 (gather reads x directly, fp32)
    k_buildA3<<<bA_grid, 256, 0, stream>>>(x, cnt, offs, sorted, A);
    k_gemm3<<<gemm_grid, 64, 0, stream>>>(A, Bt1, b1, h1, stats1);

    // layer 2
    k_castbn<<<(N_NODES * DIM / 4 + 255) / 256, 256, 0, stream>>>(h1, stats1, g1, be1, xr);
    k_buildA3<<<bA_grid, 256, 0, stream>>>(xr, cnt, offs, sorted, A);
    k_gemm3<<<gemm_grid, 64, 0, stream>>>(A, Bt2, b2, h2, stats2);

    k_classifier<<<(N_NODES + 3) / 4, 256, 0, stream>>>(h2, stats2, g2, be2, cw, cb, out);
}